// Round 15
// baseline (249.649 us; speedup 1.0000x reference)
//
#include <hip/hip_runtime.h>
#include <math.h>
#include <stdint.h>

// BS=8, ROI=512, D=1024, G=16, DH=64, GEO=64, N_total=4096
// All I/O float32.

using f16   = _Float16;
using f16x2 = __attribute__((ext_vector_type(2))) f16;
using f16x4 = __attribute__((ext_vector_type(4))) f16;
using f16x8 = __attribute__((ext_vector_type(8))) f16;
using f32x4 = __attribute__((ext_vector_type(4))) float;

// hardware transcendentals (avoid glibc macro collisions with __exp2f/__log2f)
__device__ __forceinline__ float hw_exp2(float x) { return __builtin_amdgcn_exp2f(x); }
__device__ __forceinline__ float hw_log2(float x) { return __builtin_amdgcn_logf(x); }

// v_cvt_pkrtz_f16_f32 returns __fp16x2; bit-cast to our f16x2 (same layout)
__device__ __forceinline__ f16x2 cvt_pk(float a, float b) {
    return __builtin_bit_cast(f16x2, __builtin_amdgcn_cvt_pkrtz(a, b));
}

// async 16B/lane global->LDS copy; lds dest is wave-uniform, HW adds lane*16
__device__ __forceinline__ void cp16(void* lds, const void* g) {
    __builtin_amdgcn_global_load_lds(
        (const __attribute__((address_space(1))) uint32_t*)g,
        (__attribute__((address_space(3))) uint32_t*)lds, 16, 0, 0);
}

// ------------------- geometry + per-box geo tables (merged geom/ab):
// gcx,gcy,gw per box. Tables are PRE-SCALED by 2*log2(e) so the tanh arg
// feeds exp2 directly (ln2 * 2log2e == 2 exactly -> W cols scale by 2.0 in geo).
// ABb[i][d] = S285*(lw*W2[d] + lh*W3[d])
// ABa[i][d] = S285*(lw*W2[d] + lh*W3[d] + b_geo[d] - lw*(W0[d]+W1[d]))
__global__ __launch_bounds__(256) void geom_ab_kernel(
    const float* __restrict__ boxes, const float* __restrict__ W_geo,
    const float* __restrict__ b_geo,
    float* __restrict__ gcx, float* __restrict__ gcy, float* __restrict__ gw,
    float* __restrict__ ABa, float* __restrict__ ABb)
{
    const float S285 = 2.8853900817779268f;   // 2*log2(e)
    const int i = (blockIdx.x << 2) + (threadIdx.x >> 6);
    const int d = threadIdx.x & 63;
    const float x1 = boxes[i * 4 + 0];
    const float y1 = boxes[i * 4 + 1];
    const float x2 = boxes[i * 4 + 2];
    const float y2 = boxes[i * 4 + 3];
    const float w = x2 - x1, h = y2 - y1;
    const float lw = logf(w), lh = logf(h);
    if (d == 0) {
        gcx[i] = 0.5f * (x1 + x2);
        gcy[i] = 0.5f * (y1 + y2);
        gw[i]  = w;
    }
    const float4 wr = *reinterpret_cast<const float4*>(W_geo + (d << 2));
    const float bv = fmaf(lw, wr.z, lh * wr.w);
    ABb[i * 64 + d] = bv * S285;
    ABa[i * 64 + d] = (bv + b_geo[d] - lw * (wr.x + wr.y)) * S285;
}

// ------------------------------------------------- fp32 -> SINGLE f16 pack
// dst row: 1024 f16; 64-f16 chunks (k 64c..64c+64), in-chunk idx ^ ((row&7)<<3).
__device__ __forceinline__ void pack_row1(const float* __restrict__ src,
                                          f16* __restrict__ dst, int m, int tid)
{
    const int k = tid << 2;
    const float4 v = *reinterpret_cast<const float4*>(src + (size_t)m * 1024 + k);
    f16x4 a;
    a[0] = (f16)v.x; a[1] = (f16)v.y; a[2] = (f16)v.z; a[3] = (f16)v.w;
    const int sw = (m & 7) << 3;
    *reinterpret_cast<f16x4*>(dst + (size_t)m * 1024 + (k & ~63) + ((k & 63) ^ sw)) = a;
}

// one launch packs x, W_q, W_k, W_gc
__global__ __launch_bounds__(256) void pack4_kernel(
    const float* __restrict__ x,  const float* __restrict__ Wq,
    const float* __restrict__ Wk, const float* __restrict__ Wg,
    f16* __restrict__ xs, f16* __restrict__ wqs,
    f16* __restrict__ wks, f16* __restrict__ wgs)
{
    const int bid = blockIdx.x;
    const float* src; f16* dst; int m;
    if (bid < 4096)      { src = x;  dst = xs;  m = bid; }
    else if (bid < 5120) { src = Wq; dst = wqs; m = bid - 4096; }
    else if (bid < 6144) { src = Wk; dst = wks; m = bid - 5120; }
    else                 { src = Wg; dst = wgs; m = bid - 6144; }
    pack_row1(src, dst, m, threadIdx.x);
}

// ---------------------------------------- Q & K projections, SINGLE-f16 MFMA
// 128x128 tile, 512 threads = 8 waves (2x4 wave-grid, 64x32 wave-tile).
// Epilogue writes PACKED f16 directly.
__global__ __launch_bounds__(512) void gemm_qk_f16(
    const f16* __restrict__ xs, const f16* __restrict__ wqs, const f16* __restrict__ wks,
    const float* __restrict__ b_q, const float* __restrict__ b_k,
    f16* __restrict__ qp, f16* __restrict__ kp)
{
    const bool isK = (blockIdx.z != 0);
    const f16* Bmat   = isK ? wks : wqs;
    const float* bias = isK ? b_k : b_q;
    f16* Cp           = isK ? kp : qp;
    const int m0 = blockIdx.y << 7;
    const int n0 = blockIdx.x << 7;

    __shared__ f16 As[8192];   // [128 rows][64 f16], swizzled content
    __shared__ f16 Bs[8192];

    const int tid  = threadIdx.x;
    const int lane = tid & 63;
    const int w    = tid >> 6;          // 0..7
    const int wr   = (w >> 2) << 6;     // 0/64
    const int wc   = (w & 3) << 5;      // 0/32/64/96
    const int srow = lane >> 3;
    const int sseg = (lane & 7) << 4;
    const int l15  = lane & 15;
    const int kgrp = (lane >> 4) << 3;

    f32x4 acc[4][2] = {};

    int aoff[4], boff[2];
    #pragma unroll
    for (int f = 0; f < 4; ++f) {
        const int ra = wr + (f << 4) + l15;
        aoff[f] = (ra << 6) + (kgrp ^ ((ra & 7) << 3));
    }
    #pragma unroll
    for (int f = 0; f < 2; ++f) {
        const int rb = wc + (f << 4) + l15;
        boff[f] = (rb << 6) + (kgrp ^ ((rb & 7) << 3));
    }

    for (int s = 0; s < 16; ++s) {
        const size_t gb = (size_t)(s << 7) + sseg;
        #pragma unroll
        for (int it = 0; it < 2; ++it) {
            const int ch = (w << 1) + it;        // 0..15
            const int gr = (ch << 3) + srow;
            cp16((char*)As + (ch << 10), (const char*)xs   + (size_t)(m0 + gr) * 2048 + gb);
            cp16((char*)Bs + (ch << 10), (const char*)Bmat + (size_t)(n0 + gr) * 2048 + gb);
        }
        __syncthreads();

        f16x8 a0[4], a1[4], b0[2], b1[2];
        #pragma unroll
        for (int f = 0; f < 4; ++f) {
            a0[f] = *reinterpret_cast<const f16x8*>(As + aoff[f]);
            a1[f] = *reinterpret_cast<const f16x8*>(As + (aoff[f] ^ 32));
        }
        #pragma unroll
        for (int f = 0; f < 2; ++f) {
            b0[f] = *reinterpret_cast<const f16x8*>(Bs + boff[f]);
            b1[f] = *reinterpret_cast<const f16x8*>(Bs + (boff[f] ^ 32));
        }
        #pragma unroll
        for (int i = 0; i < 4; ++i)
            #pragma unroll
            for (int j = 0; j < 2; ++j) {
                acc[i][j] = __builtin_amdgcn_mfma_f32_16x16x32_f16(a0[i], b0[j], acc[i][j], 0, 0, 0);
                acc[i][j] = __builtin_amdgcn_mfma_f32_16x16x32_f16(a1[i], b1[j], acc[i][j], 0, 0, 0);
            }
        __syncthreads();
    }

    const int rgrp = (lane >> 4) << 2;
    #pragma unroll
    for (int j = 0; j < 2; ++j) {
        const int col = n0 + wc + (j << 4) + l15;
        const float bv = bias[col];
        const int chi = col & ~63, clo = col & 63;
        #pragma unroll
        for (int i = 0; i < 4; ++i) {
            const int row = m0 + wr + (i << 4) + rgrp;
            #pragma unroll
            for (int r = 0; r < 4; ++r) {
                const int rr = row + r;
                const int sw = (rr & 7) << 3;
                Cp[(size_t)rr * 1024 + chi + (clo ^ sw)] = (f16)(acc[i][j][r] + bv);
            }
        }
    }
}

// -------------------- y_t[b,g,o,j] = sum_d x[b,j,d]*W_gc[g,o,d], SINGLE-f16
// Output: packed f16 [z][o=64][512 f16], 64-j superchunks swizzled by (o&7)<<3.
__global__ __launch_bounds__(256) void gemm_yt_f16(
    const f16* __restrict__ xs, const f16* __restrict__ wgs,
    f16* __restrict__ Yt)
{
    const int z = blockIdx.z;            // b*16+g
    const int b = z >> 4, g = z & 15;
    const int m0 = blockIdx.y << 7;      // j tile base
    const f16* A    = xs  + (size_t)(b << 9) * 1024;
    const f16* Bmat = wgs + (size_t)(g << 6) * 1024;

    __shared__ f16 As[8192];   // [128][64]
    __shared__ f16 Bs[4096];   // [64][64]

    const int tid  = threadIdx.x;
    const int lane = tid & 63;
    const int w    = tid >> 6;
    const int wr   = (w >> 1) << 6;
    const int wc   = (w & 1) << 5;
    const int srow = lane >> 3;
    const int sseg = (lane & 7) << 4;
    const int l15  = lane & 15;
    const int kgrp = (lane >> 4) << 3;

    f32x4 acc[4][2] = {};

    int aoff[4], boff[2];
    #pragma unroll
    for (int f = 0; f < 4; ++f) {
        const int ra = wr + (f << 4) + l15;
        aoff[f] = (ra << 6) + (kgrp ^ ((ra & 7) << 3));
    }
    #pragma unroll
    for (int f = 0; f < 2; ++f) {
        const int rb = wc + (f << 4) + l15;
        boff[f] = (rb << 6) + (kgrp ^ ((rb & 7) << 3));
    }

    for (int s = 0; s < 16; ++s) {
        const size_t gb = (size_t)(s << 7) + sseg;
        #pragma unroll
        for (int it = 0; it < 4; ++it) {
            const int ch = (w << 2) + it;
            cp16((char*)As + (ch << 10),
                 (const char*)A + (size_t)(m0 + (ch << 3) + srow) * 2048 + gb);
        }
        #pragma unroll
        for (int it = 0; it < 2; ++it) {
            const int ch = (w << 1) + it;
            cp16((char*)Bs + (ch << 10),
                 (const char*)Bmat + (size_t)((ch << 3) + srow) * 2048 + gb);
        }
        __syncthreads();

        f16x8 a0[4], a1[4], b0[2], b1[2];
        #pragma unroll
        for (int f = 0; f < 4; ++f) {
            a0[f] = *reinterpret_cast<const f16x8*>(As + aoff[f]);
            a1[f] = *reinterpret_cast<const f16x8*>(As + (aoff[f] ^ 32));
        }
        #pragma unroll
        for (int f = 0; f < 2; ++f) {
            b0[f] = *reinterpret_cast<const f16x8*>(Bs + boff[f]);
            b1[f] = *reinterpret_cast<const f16x8*>(Bs + (boff[f] ^ 32));
        }
        #pragma unroll
        for (int i = 0; i < 4; ++i)
            #pragma unroll
            for (int j = 0; j < 2; ++j) {
                acc[i][j] = __builtin_amdgcn_mfma_f32_16x16x32_f16(b0[j], a0[i], acc[i][j], 0, 0, 0);
                acc[i][j] = __builtin_amdgcn_mfma_f32_16x16x32_f16(b1[j], a1[i], acc[i][j], 0, 0, 0);
            }
        __syncthreads();
    }

    const int rgrp = (lane >> 4) << 2;
    #pragma unroll
    for (int jj = 0; jj < 2; ++jj) {
        const int obase = wc + (jj << 4) + rgrp;
        #pragma unroll
        for (int i = 0; i < 4; ++i) {
            const int jcol = m0 + wr + (i << 4) + l15;
            const int jhi = (jcol >> 6) << 6, jlo = jcol & 63;
            #pragma unroll
            for (int r = 0; r < 4; ++r) {
                const int o = obase + r;
                Yt[((size_t)z << 15) + (o << 9) + jhi + (jlo ^ ((o & 7) << 3))]
                    = (f16)acc[i][jj][r];
            }
        }
    }
}

// ---------------- geo MLP -> S[z][i][j] = clamped softmax WEIGHT (f16)
// R9 config (grid (128,8), 4 waves = 4 i-rows, no inner barriers, reg prefetch)
// + VALU cuts: (a) tables pre-scaled by 2log2e so tanh arg feeds exp2 directly;
// (b) hi/lo split via mantissa MASK (exact under RTZ cvt); (c) v_cvt_pkrtz
// packs 2 f32->2 f16 per instruction into the fragment.
// H and W_bgc keep the hi/lo split (6 MFMA) — R3 failure proved it necessary.
__global__ __launch_bounds__(256, 4) void geo_mfma(
    const float* __restrict__ gcx, const float* __restrict__ gcy,
    const float* __restrict__ gw,
    const float* __restrict__ ABa, const float* __restrict__ ABb,
    const float* __restrict__ W_geo, const float* __restrict__ W_bgc,
    const float* __restrict__ b_bgc,
    f16* __restrict__ S)
{
    __shared__ float2 sJ[512];   // 4 KB

    const int tid  = threadIdx.x;
    const int lane = tid & 63;
    const int h    = lane >> 4;
    const int p    = lane & 15;
    const int w    = tid >> 6;
    const int bb   = blockIdx.y;
    const int irow = (blockIdx.x << 2) + w;
    const int ig   = (bb << 9) + irow;

    // W0,W1 (x 2.0: ln2 * 2log2e == 2) for dA = 8h+e, dB = 32+8h+e
    float2 wA[8], wB[8];
    #pragma unroll
    for (int e = 0; e < 8; ++e) {
        const float4 t0 = *reinterpret_cast<const float4*>(W_geo + (((h << 3) + e) << 2));
        wA[e] = make_float2(t0.x * 2.0f, t0.y * 2.0f);
        const float4 t1 = *reinterpret_cast<const float4*>(W_geo + ((32 + (h << 3) + e) << 2));
        wB[e] = make_float2(t1.x * 2.0f, t1.y * 2.0f);
    }
    float aiA[8], aiB[8];
    {
        const float4 a0 = *reinterpret_cast<const float4*>(ABa + ig * 64 + (h << 3));
        const float4 a1 = *reinterpret_cast<const float4*>(ABa + ig * 64 + (h << 3) + 4);
        aiA[0] = a0.x; aiA[1] = a0.y; aiA[2] = a0.z; aiA[3] = a0.w;
        aiA[4] = a1.x; aiA[5] = a1.y; aiA[6] = a1.z; aiA[7] = a1.w;
        const float4 b0 = *reinterpret_cast<const float4*>(ABa + ig * 64 + 32 + (h << 3));
        const float4 b1 = *reinterpret_cast<const float4*>(ABa + ig * 64 + 32 + (h << 3) + 4);
        aiB[0] = b0.x; aiB[1] = b0.y; aiB[2] = b0.z; aiB[3] = b0.w;
        aiB[4] = b1.x; aiB[5] = b1.y; aiB[6] = b1.z; aiB[7] = b1.w;
    }
    // W_bgc A-frags (row g = p), hi/lo split
    f16x8 wbh0, wbl0, wbh1, wbl1;
    #pragma unroll
    for (int e = 0; e < 8; ++e) {
        const float v0 = W_bgc[(p << 6) + (h << 3) + e];
        const f16 x0 = (f16)v0; wbh0[e] = x0; wbl0[e] = (f16)(v0 - (float)x0);
        const float v1 = W_bgc[(p << 6) + 32 + (h << 3) + e];
        const f16 x1 = (f16)v1; wbh1[e] = x1; wbl1[e] = (f16)(v1 - (float)x1);
    }
    float bb4[4];
    #pragma unroll
    for (int r = 0; r < 4; ++r) bb4[r] = b_bgc[(h << 2) + r];

    const float cxi = gcx[ig], cyi = gcy[ig];
    const float ti  = 1e-3f * gw[ig];

    for (int l = tid; l < 512; l += 256) {
        const int jg = (bb << 9) + l;
        sJ[l] = make_float2(gcx[jg], gcy[jg]);
    }
    __syncthreads();

    // Bj rows for this lane: ABb[(bb*512 + jc*16 + p)][8h+e / 32+8h+e]
    const float* bjrow = ABb + ((size_t)(bb << 9) << 6) + (p << 6) + (h << 3);
    float4 cA0 = *reinterpret_cast<const float4*>(bjrow);
    float4 cA1 = *reinterpret_cast<const float4*>(bjrow + 4);
    float4 cB0 = *reinterpret_cast<const float4*>(bjrow + 32);
    float4 cB1 = *reinterpret_cast<const float4*>(bjrow + 36);

    f16* sp = S + (((size_t)((bb << 4) + (h << 2))) << 18) + ((size_t)irow << 9) + p;

    union F16x8u { f16x8 v; f16x2 h[4]; };

    for (int jc = 0; jc < 32; ++jc) {
        float4 nA0, nA1, nB0, nB1;
        if (jc < 31) {
            const float* nx = bjrow + ((jc + 1) << 10);   // +16 rows * 64
            nA0 = *reinterpret_cast<const float4*>(nx);
            nA1 = *reinterpret_cast<const float4*>(nx + 4);
            nB0 = *reinterpret_cast<const float4*>(nx + 32);
            nB1 = *reinterpret_cast<const float4*>(nx + 36);
        }
        const float2 je = sJ[(jc << 4) + p];
        const float e0 = hw_log2(fmaxf(fabsf(cxi - je.x), ti));
        const float e1 = hw_log2(fmaxf(fabsf(cyi - je.y), ti));

        const float bjA[8] = {cA0.x, cA0.y, cA0.z, cA0.w, cA1.x, cA1.y, cA1.z, cA1.w};
        const float bjB[8] = {cB0.x, cB0.y, cB0.z, cB0.w, cB1.x, cB1.y, cB1.z, cB1.w};

        F16x8u hhA, hlA, hhB, hlB;
        #pragma unroll
        for (int k = 0; k < 4; ++k) {
            float tv[2], uv[2];
            #pragma unroll
            for (int s = 0; s < 2; ++s) {
                const int e = (k << 1) + s;
                // arg already scaled by 2log2e: tanh(x) = 1 - 2/(exp2(arg)+1)
                float t = fmaf(e0, wA[e].x, fmaf(e1, wA[e].y, aiA[e] - bjA[e]));
                tv[s] = fmaf(-2.0f, __builtin_amdgcn_rcpf(hw_exp2(t) + 1.0f), 1.0f);
                float u = fmaf(e0, wB[e].x, fmaf(e1, wB[e].y, aiB[e] - bjB[e]));
                uv[s] = fmaf(-2.0f, __builtin_amdgcn_rcpf(hw_exp2(u) + 1.0f), 1.0f);
            }
            // mask-split: keep 10 mantissa bits -> exact under RTZ f16 convert
            const float th0 = __uint_as_float(__float_as_uint(tv[0]) & 0xFFFFE000u);
            const float th1 = __uint_as_float(__float_as_uint(tv[1]) & 0xFFFFE000u);
            hhA.h[k] = cvt_pk(th0, th1);
            hlA.h[k] = cvt_pk(tv[0] - th0, tv[1] - th1);
            const float uh0 = __uint_as_float(__float_as_uint(uv[0]) & 0xFFFFE000u);
            const float uh1 = __uint_as_float(__float_as_uint(uv[1]) & 0xFFFFE000u);
            hhB.h[k] = cvt_pk(uh0, uh1);
            hlB.h[k] = cvt_pk(uv[0] - uh0, uv[1] - uh1);
        }
        f32x4 acc = {0.f, 0.f, 0.f, 0.f};
        acc = __builtin_amdgcn_mfma_f32_16x16x32_f16(wbh0, hhA.v, acc, 0, 0, 0);
        acc = __builtin_amdgcn_mfma_f32_16x16x32_f16(wbh0, hlA.v, acc, 0, 0, 0);
        acc = __builtin_amdgcn_mfma_f32_16x16x32_f16(wbl0, hhA.v, acc, 0, 0, 0);
        acc = __builtin_amdgcn_mfma_f32_16x16x32_f16(wbh1, hhB.v, acc, 0, 0, 0);
        acc = __builtin_amdgcn_mfma_f32_16x16x32_f16(wbh1, hlB.v, acc, 0, 0, 0);
        acc = __builtin_amdgcn_mfma_f32_16x16x32_f16(wbl1, hhB.v, acc, 0, 0, 0);

        #pragma unroll
        for (int r = 0; r < 4; ++r)
            sp[((size_t)r << 18) + (jc << 4)] = (f16)fmaxf(acc[r] + bb4[r], 1e-6f);

        cA0 = nA0; cA1 = nA1; cB0 = nB0; cB1 = nB1;
    }
}

// ---------------- fused logits + softmax + PV. Per block: (z, 16 i-rows).
__global__ __launch_bounds__(256) void attn_fused(
    const f16* __restrict__ qp, const f16* __restrict__ kp,
    const f16* __restrict__ Sb, const f16* __restrict__ Yt,
    const float* __restrict__ b_gc, float* __restrict__ out)
{
    __shared__ float Ss[16][514];   // ~33 KB
    __shared__ f16   P[16 * 512];   // 16 KB

    const int tid  = threadIdx.x;
    const int lane = tid & 63;
    const int w    = tid >> 6;
    const int h    = lane >> 4;
    const int p_   = lane & 15;
    const int kgrp = h << 3;
    const int i0   = blockIdx.x << 4;
    const int z    = blockIdx.y;
    const int b    = z >> 4, g = z & 15;

    const char* qbytes = (const char*)qp + ((size_t)((b << 9) + i0)) * 2048 + (g << 7);
    const char* kbytes = (const char*)kp + ((size_t)(b << 9)) * 2048 + (g << 7);

    // q A-frags direct from global (A row = i = p_)
    f16x8 aq[2];
    {
        const char* qrow = qbytes + (size_t)p_ * 2048;
        #pragma unroll
        for (int s = 0; s < 2; ++s) {
            const int bo = ((s << 5) + kgrp) ^ ((p_ & 7) << 3);
            aq[s] = *reinterpret_cast<const f16x8*>(qrow + bo * 2);
        }
    }

    // ---- logits: each wave owns j in [w*128, w*128+128)
    #pragma unroll
    for (int f = 0; f < 8; ++f) {
        const int j = (w << 7) + (f << 4) + p_;
        const char* krow = kbytes + (size_t)j * 2048;
        f32x4 a = {0.f, 0.f, 0.f, 0.f};
        #pragma unroll
        for (int s = 0; s < 2; ++s) {
            const int bo = ((s << 5) + kgrp) ^ ((j & 7) << 3);
            const f16x8 bk = *reinterpret_cast<const f16x8*>(krow + bo * 2);
            a = __builtin_amdgcn_mfma_f32_16x16x32_f16(aq[s], bk, a, 0, 0, 0);
        }
        #pragma unroll
        for (int r = 0; r < 4; ++r)
            Ss[(h << 2) + r][(w << 7) + (f << 4) + p_] = 0.125f * a[r];
    }
    __syncthreads();

    // ---- softmax with geo-weight multiply (4 rows per wave)
    #pragma unroll
    for (int rr = 0; rr < 4; ++rr) {
        const int row = (w << 2) + rr;
        const f16* wbp = Sb + ((size_t)z << 18) + ((size_t)(i0 + row) << 9);
        float l[8];
        float m = -3.0e38f;
        #pragma unroll
        for (int t = 0; t < 8; ++t) { l[t] = Ss[row][(t << 6) + lane]; m = fmaxf(m, l[t]); }
        #pragma unroll
        for (int off = 32; off > 0; off >>= 1) m = fmaxf(m, __shfl_xor(m, off));
        float wb[8];
        #pragma unroll
        for (int t = 0; t < 8; ++t) wb[t] = (float)wbp[(t << 6) + lane];
        float ssum = 0.f;
        #pragma unroll
        for (int t = 0; t < 8; ++t) { l[t] = wb[t] * __expf(l[t] - m); ssum += l[t]; }
        #pragma unroll
        for (int off = 32; off > 0; off >>= 1) ssum += __shfl_xor(ssum, off);
        const float inv = 1.0f / ssum;
        const int sw = (row & 7) << 3;
        f16* prow = P + (row << 9);
        #pragma unroll
        for (int t = 0; t < 8; ++t)
            prow[(t << 6) + (lane ^ sw)] = (f16)(l[t] * inv);
    }
    __syncthreads();

    // ---- PV: out 16i x 64o; wave w owns o-frag [w*16, w*16+16)
    const int o = (w << 4) + p_;
    const f16* ytz = Yt + ((size_t)z << 15) + ((size_t)o << 9);
    const f16* pr  = P + (p_ << 9);
    f32x4 av = {0.f, 0.f, 0.f, 0.f};
    #pragma unroll
    for (int t = 0; t < 8; ++t) {
        #pragma unroll
        for (int s = 0; s < 2; ++s) {
            const int ko = (s << 5) + kgrp;
            const f16x8 bf = *reinterpret_cast<const f16x8*>(ytz + (t << 6) + (ko ^ ((o  & 7) << 3)));
            const f16x8 af = *reinterpret_cast<const f16x8*>(pr  + (t << 6) + (ko ^ ((p_ & 7) << 3)));
            av = __builtin_amdgcn_mfma_f32_16x16x32_f16(af, bf, av, 0, 0, 0);
        }
    }
    const float bg = b_gc[(g << 6) + o];
    float* orow = out + ((size_t)((b << 9) + i0)) * 1024 + (g << 6) + o;
    #pragma unroll
    for (int r = 0; r < 4; ++r)
        orow[(size_t)((h << 2) + r) * 1024] = fmaxf(av[r] + bg, 0.f);
}

// ---------------------------------------------------------------- launch
extern "C" void kernel_launch(void* const* d_in, const int* in_sizes, int n_in,
                              void* d_out, int out_size, void* d_ws, size_t ws_size,
                              hipStream_t stream)
{
    (void)in_sizes; (void)n_in; (void)out_size; (void)ws_size;
    const float* x     = (const float*)d_in[0];
    const float* boxes = (const float*)d_in[1];
    const float* W_geo = (const float*)d_in[2];
    const float* b_geo = (const float*)d_in[3];
    const float* W_bgc = (const float*)d_in[4];
    const float* b_bgc = (const float*)d_in[5];
    const float* W_q   = (const float*)d_in[6];
    const float* b_q   = (const float*)d_in[7];
    const float* W_k   = (const float*)d_in[8];
    const float* b_k   = (const float*)d_in[9];
    const float* W_gc  = (const float*)d_in[10];
    const float* b_gc  = (const float*)d_in[11];
    float* out = (float*)d_out;

    float* fws = (float*)d_ws;
    float* gcx = fws;
    float* gcy = gcx + 4096;
    float* gw  = gcy + 4096;
    float* ABa = gw + 4096;                       // [4096][64] f32 = 1 MB
    float* ABb = ABa + 4096 * 64;                 // [4096][64] f32 = 1 MB
    f16* qp  = (f16*)(ABb + 4096 * 64);           // [4096][1024] f16  8.4 MB
    f16* kp  = qp + (size_t)4096 * 1024;          // [4096][1024] f16  8.4 MB
    f16* ytp = kp + (size_t)4096 * 1024;          // [128][64][512] f16 8.4 MB
    f16* Sws = ytp + (size_t)128 * 64 * 512;      // [128][512][512] f16 67.1 MB

    // pack scratch aliased into Sws head (consumed before geo_mfma writes Sws)
    f16* xs  = Sws;                               // [4096][1024] f16 8.4 MB
    f16* wqs = xs  + (size_t)4096 * 1024;
    f16* wks = wqs + (size_t)1024 * 1024;
    f16* wgs = wks + (size_t)1024 * 1024;

    geom_ab_kernel<<<1024, 256, 0, stream>>>(boxes, W_geo, b_geo, gcx, gcy, gw, ABa, ABb);
    pack4_kernel<<<7168, 256, 0, stream>>>(x, W_q, W_k, W_gc, xs, wqs, wks, wgs);
    gemm_qk_f16<<<dim3(8, 32, 2), 512, 0, stream>>>(xs, wqs, wks, b_q, b_k, qp, kp);
    gemm_yt_f16<<<dim3(1, 4, 128), 256, 0, stream>>>(xs, wgs, ytp);
    geo_mfma<<<dim3(128, 8), 256, 0, stream>>>(gcx, gcy, gw, ABa, ABb,
                                               W_geo, W_bgc, b_bgc, Sws);
    attn_fused<<<dim3(32, 128), 256, 0, stream>>>(qp, kp, Sws, ytp, b_gc, out);
}

// Round 16
// 241.654 us; speedup vs baseline: 1.0331x; 1.0331x over previous
//
#include <hip/hip_runtime.h>
#include <math.h>
#include <stdint.h>

// BS=8, ROI=512, D=1024, G=16, DH=64, GEO=64, N_total=4096
// All I/O float32.

using f16   = _Float16;
using f16x2 = __attribute__((ext_vector_type(2))) f16;
using f16x4 = __attribute__((ext_vector_type(4))) f16;
using f16x8 = __attribute__((ext_vector_type(8))) f16;
using f32x4 = __attribute__((ext_vector_type(4))) float;

// hardware transcendentals (avoid glibc macro collisions with __exp2f/__log2f)
__device__ __forceinline__ float hw_exp2(float x) { return __builtin_amdgcn_exp2f(x); }
__device__ __forceinline__ float hw_log2(float x) { return __builtin_amdgcn_logf(x); }

// v_cvt_pkrtz_f16_f32 returns __fp16x2; bit-cast to our f16x2 (same layout)
__device__ __forceinline__ f16x2 cvt_pk(float a, float b) {
    return __builtin_bit_cast(f16x2, __builtin_amdgcn_cvt_pkrtz(a, b));
}

// async 16B/lane global->LDS copy; lds dest is wave-uniform, HW adds lane*16
__device__ __forceinline__ void cp16(void* lds, const void* g) {
    __builtin_amdgcn_global_load_lds(
        (const __attribute__((address_space(1))) uint32_t*)g,
        (__attribute__((address_space(3))) uint32_t*)lds, 16, 0, 0);
}

// ------------------- geometry + per-box geo tables (merged geom/ab):
// gcx,gcy,gw per box. Tables PRE-SCALED by 2*log2(e).
// ABa[i][d]  (row-major) = S285*(lw*W2+lh*W3 + b_geo - lw*(W0+W1))  [i-side]
// ABbT tiled TRANSPOSED: ABbT[(i>>4)*1024 + d*16 + (i&15)] = S285*(lw*W2+lh*W3)
//   -> geo's 16-lane groups read 16 CONSECUTIVE floats (64B segments), fixing
//      the 64-segments-per-load scatter that R15 analysis identified.
__global__ __launch_bounds__(256) void geom_ab_kernel(
    const float* __restrict__ boxes, const float* __restrict__ W_geo,
    const float* __restrict__ b_geo,
    float* __restrict__ gcx, float* __restrict__ gcy, float* __restrict__ gw,
    float* __restrict__ ABa, float* __restrict__ ABbT)
{
    const float S285 = 2.8853900817779268f;   // 2*log2(e)
    const int i = (blockIdx.x << 2) + (threadIdx.x >> 6);
    const int d = threadIdx.x & 63;
    const float x1 = boxes[i * 4 + 0];
    const float y1 = boxes[i * 4 + 1];
    const float x2 = boxes[i * 4 + 2];
    const float y2 = boxes[i * 4 + 3];
    const float w = x2 - x1, h = y2 - y1;
    const float lw = logf(w), lh = logf(h);
    if (d == 0) {
        gcx[i] = 0.5f * (x1 + x2);
        gcy[i] = 0.5f * (y1 + y2);
        gw[i]  = w;
    }
    const float4 wr = *reinterpret_cast<const float4*>(W_geo + (d << 2));
    const float bv = fmaf(lw, wr.z, lh * wr.w);
    ABbT[((i >> 4) << 10) + (d << 4) + (i & 15)] = bv * S285;
    ABa[i * 64 + d] = (bv + b_geo[d] - lw * (wr.x + wr.y)) * S285;
}

// ------------------------------------------------- fp32 -> SINGLE f16 pack
// dst row: 1024 f16; 64-f16 chunks (k 64c..64c+64), in-chunk idx ^ ((row&7)<<3).
__device__ __forceinline__ void pack_row1(const float* __restrict__ src,
                                          f16* __restrict__ dst, int m, int tid)
{
    const int k = tid << 2;
    const float4 v = *reinterpret_cast<const float4*>(src + (size_t)m * 1024 + k);
    f16x4 a;
    a[0] = (f16)v.x; a[1] = (f16)v.y; a[2] = (f16)v.z; a[3] = (f16)v.w;
    const int sw = (m & 7) << 3;
    *reinterpret_cast<f16x4*>(dst + (size_t)m * 1024 + (k & ~63) + ((k & 63) ^ sw)) = a;
}

// one launch packs x, W_q, W_k, W_gc
__global__ __launch_bounds__(256) void pack4_kernel(
    const float* __restrict__ x,  const float* __restrict__ Wq,
    const float* __restrict__ Wk, const float* __restrict__ Wg,
    f16* __restrict__ xs, f16* __restrict__ wqs,
    f16* __restrict__ wks, f16* __restrict__ wgs)
{
    const int bid = blockIdx.x;
    const float* src; f16* dst; int m;
    if (bid < 4096)      { src = x;  dst = xs;  m = bid; }
    else if (bid < 5120) { src = Wq; dst = wqs; m = bid - 4096; }
    else if (bid < 6144) { src = Wk; dst = wks; m = bid - 5120; }
    else                 { src = Wg; dst = wgs; m = bid - 6144; }
    pack_row1(src, dst, m, threadIdx.x);
}

// ---------------------------------------- Q & K projections, SINGLE-f16 MFMA
// 128x128 tile, 512 threads = 8 waves (2x4 wave-grid, 64x32 wave-tile).
// Epilogue writes PACKED f16 directly.
__global__ __launch_bounds__(512) void gemm_qk_f16(
    const f16* __restrict__ xs, const f16* __restrict__ wqs, const f16* __restrict__ wks,
    const float* __restrict__ b_q, const float* __restrict__ b_k,
    f16* __restrict__ qp, f16* __restrict__ kp)
{
    const bool isK = (blockIdx.z != 0);
    const f16* Bmat   = isK ? wks : wqs;
    const float* bias = isK ? b_k : b_q;
    f16* Cp           = isK ? kp : qp;
    const int m0 = blockIdx.y << 7;
    const int n0 = blockIdx.x << 7;

    __shared__ f16 As[8192];   // [128 rows][64 f16], swizzled content
    __shared__ f16 Bs[8192];

    const int tid  = threadIdx.x;
    const int lane = tid & 63;
    const int w    = tid >> 6;          // 0..7
    const int wr   = (w >> 2) << 6;     // 0/64
    const int wc   = (w & 3) << 5;      // 0/32/64/96
    const int srow = lane >> 3;
    const int sseg = (lane & 7) << 4;
    const int l15  = lane & 15;
    const int kgrp = (lane >> 4) << 3;

    f32x4 acc[4][2] = {};

    int aoff[4], boff[2];
    #pragma unroll
    for (int f = 0; f < 4; ++f) {
        const int ra = wr + (f << 4) + l15;
        aoff[f] = (ra << 6) + (kgrp ^ ((ra & 7) << 3));
    }
    #pragma unroll
    for (int f = 0; f < 2; ++f) {
        const int rb = wc + (f << 4) + l15;
        boff[f] = (rb << 6) + (kgrp ^ ((rb & 7) << 3));
    }

    for (int s = 0; s < 16; ++s) {
        const size_t gb = (size_t)(s << 7) + sseg;
        #pragma unroll
        for (int it = 0; it < 2; ++it) {
            const int ch = (w << 1) + it;        // 0..15
            const int gr = (ch << 3) + srow;
            cp16((char*)As + (ch << 10), (const char*)xs   + (size_t)(m0 + gr) * 2048 + gb);
            cp16((char*)Bs + (ch << 10), (const char*)Bmat + (size_t)(n0 + gr) * 2048 + gb);
        }
        __syncthreads();

        f16x8 a0[4], a1[4], b0[2], b1[2];
        #pragma unroll
        for (int f = 0; f < 4; ++f) {
            a0[f] = *reinterpret_cast<const f16x8*>(As + aoff[f]);
            a1[f] = *reinterpret_cast<const f16x8*>(As + (aoff[f] ^ 32));
        }
        #pragma unroll
        for (int f = 0; f < 2; ++f) {
            b0[f] = *reinterpret_cast<const f16x8*>(Bs + boff[f]);
            b1[f] = *reinterpret_cast<const f16x8*>(Bs + (boff[f] ^ 32));
        }
        #pragma unroll
        for (int i = 0; i < 4; ++i)
            #pragma unroll
            for (int j = 0; j < 2; ++j) {
                acc[i][j] = __builtin_amdgcn_mfma_f32_16x16x32_f16(a0[i], b0[j], acc[i][j], 0, 0, 0);
                acc[i][j] = __builtin_amdgcn_mfma_f32_16x16x32_f16(a1[i], b1[j], acc[i][j], 0, 0, 0);
            }
        __syncthreads();
    }

    const int rgrp = (lane >> 4) << 2;
    #pragma unroll
    for (int j = 0; j < 2; ++j) {
        const int col = n0 + wc + (j << 4) + l15;
        const float bv = bias[col];
        const int chi = col & ~63, clo = col & 63;
        #pragma unroll
        for (int i = 0; i < 4; ++i) {
            const int row = m0 + wr + (i << 4) + rgrp;
            #pragma unroll
            for (int r = 0; r < 4; ++r) {
                const int rr = row + r;
                const int sw = (rr & 7) << 3;
                Cp[(size_t)rr * 1024 + chi + (clo ^ sw)] = (f16)(acc[i][j][r] + bv);
            }
        }
    }
}

// -------------------- y_t[b,g,o,j] = sum_d x[b,j,d]*W_gc[g,o,d], SINGLE-f16
// Output: packed f16 [z][o=64][512 f16], 64-j superchunks swizzled by (o&7)<<3.
__global__ __launch_bounds__(256) void gemm_yt_f16(
    const f16* __restrict__ xs, const f16* __restrict__ wgs,
    f16* __restrict__ Yt)
{
    const int z = blockIdx.z;            // b*16+g
    const int b = z >> 4, g = z & 15;
    const int m0 = blockIdx.y << 7;      // j tile base
    const f16* A    = xs  + (size_t)(b << 9) * 1024;
    const f16* Bmat = wgs + (size_t)(g << 6) * 1024;

    __shared__ f16 As[8192];   // [128][64]
    __shared__ f16 Bs[4096];   // [64][64]

    const int tid  = threadIdx.x;
    const int lane = tid & 63;
    const int w    = tid >> 6;
    const int wr   = (w >> 1) << 6;
    const int wc   = (w & 1) << 5;
    const int srow = lane >> 3;
    const int sseg = (lane & 7) << 4;
    const int l15  = lane & 15;
    const int kgrp = (lane >> 4) << 3;

    f32x4 acc[4][2] = {};

    int aoff[4], boff[2];
    #pragma unroll
    for (int f = 0; f < 4; ++f) {
        const int ra = wr + (f << 4) + l15;
        aoff[f] = (ra << 6) + (kgrp ^ ((ra & 7) << 3));
    }
    #pragma unroll
    for (int f = 0; f < 2; ++f) {
        const int rb = wc + (f << 4) + l15;
        boff[f] = (rb << 6) + (kgrp ^ ((rb & 7) << 3));
    }

    for (int s = 0; s < 16; ++s) {
        const size_t gb = (size_t)(s << 7) + sseg;
        #pragma unroll
        for (int it = 0; it < 4; ++it) {
            const int ch = (w << 2) + it;
            cp16((char*)As + (ch << 10),
                 (const char*)A + (size_t)(m0 + (ch << 3) + srow) * 2048 + gb);
        }
        #pragma unroll
        for (int it = 0; it < 2; ++it) {
            const int ch = (w << 1) + it;
            cp16((char*)Bs + (ch << 10),
                 (const char*)Bmat + (size_t)((ch << 3) + srow) * 2048 + gb);
        }
        __syncthreads();

        f16x8 a0[4], a1[4], b0[2], b1[2];
        #pragma unroll
        for (int f = 0; f < 4; ++f) {
            a0[f] = *reinterpret_cast<const f16x8*>(As + aoff[f]);
            a1[f] = *reinterpret_cast<const f16x8*>(As + (aoff[f] ^ 32));
        }
        #pragma unroll
        for (int f = 0; f < 2; ++f) {
            b0[f] = *reinterpret_cast<const f16x8*>(Bs + boff[f]);
            b1[f] = *reinterpret_cast<const f16x8*>(Bs + (boff[f] ^ 32));
        }
        #pragma unroll
        for (int i = 0; i < 4; ++i)
            #pragma unroll
            for (int j = 0; j < 2; ++j) {
                acc[i][j] = __builtin_amdgcn_mfma_f32_16x16x32_f16(b0[j], a0[i], acc[i][j], 0, 0, 0);
                acc[i][j] = __builtin_amdgcn_mfma_f32_16x16x32_f16(b1[j], a1[i], acc[i][j], 0, 0, 0);
            }
        __syncthreads();
    }

    const int rgrp = (lane >> 4) << 2;
    #pragma unroll
    for (int jj = 0; jj < 2; ++jj) {
        const int obase = wc + (jj << 4) + rgrp;
        #pragma unroll
        for (int i = 0; i < 4; ++i) {
            const int jcol = m0 + wr + (i << 4) + l15;
            const int jhi = (jcol >> 6) << 6, jlo = jcol & 63;
            #pragma unroll
            for (int r = 0; r < 4; ++r) {
                const int o = obase + r;
                Yt[((size_t)z << 15) + (o << 9) + jhi + (jlo ^ ((o & 7) << 3))]
                    = (f16)acc[i][jj][r];
            }
        }
    }
}

// ---------------- geo MLP -> S[z][i][j] = clamped softmax WEIGHT (f16)
// R9 config (grid (128,8), 4 waves = 4 i-rows, no inner barriers).
// Bj loads now hit the TILED-TRANSPOSED ABbT: per 16-lane group each scalar
// dword load covers 16 consecutive floats (64B segment) -> 4 segments/instr
// instead of 64 (R15's float4 loads at row-stride-256B were 64x16B scatter).
// H and W_bgc keep the hi/lo split (6 MFMA) — R3 failure proved it necessary.
__global__ __launch_bounds__(256, 4) void geo_mfma(
    const float* __restrict__ gcx, const float* __restrict__ gcy,
    const float* __restrict__ gw,
    const float* __restrict__ ABa, const float* __restrict__ ABbT,
    const float* __restrict__ W_geo, const float* __restrict__ W_bgc,
    const float* __restrict__ b_bgc,
    f16* __restrict__ S)
{
    __shared__ float2 sJ[512];   // 4 KB

    const int tid  = threadIdx.x;
    const int lane = tid & 63;
    const int h    = lane >> 4;
    const int p    = lane & 15;
    const int w    = tid >> 6;
    const int bb   = blockIdx.y;
    const int irow = (blockIdx.x << 2) + w;
    const int ig   = (bb << 9) + irow;

    // W0,W1 (x 2.0: ln2 * 2log2e == 2) for dA = 8h+e, dB = 32+8h+e
    float2 wA[8], wB[8];
    #pragma unroll
    for (int e = 0; e < 8; ++e) {
        const float4 t0 = *reinterpret_cast<const float4*>(W_geo + (((h << 3) + e) << 2));
        wA[e] = make_float2(t0.x * 2.0f, t0.y * 2.0f);
        const float4 t1 = *reinterpret_cast<const float4*>(W_geo + ((32 + (h << 3) + e) << 2));
        wB[e] = make_float2(t1.x * 2.0f, t1.y * 2.0f);
    }
    float aiA[8], aiB[8];
    {
        const float4 a0 = *reinterpret_cast<const float4*>(ABa + ig * 64 + (h << 3));
        const float4 a1 = *reinterpret_cast<const float4*>(ABa + ig * 64 + (h << 3) + 4);
        aiA[0] = a0.x; aiA[1] = a0.y; aiA[2] = a0.z; aiA[3] = a0.w;
        aiA[4] = a1.x; aiA[5] = a1.y; aiA[6] = a1.z; aiA[7] = a1.w;
        const float4 b0 = *reinterpret_cast<const float4*>(ABa + ig * 64 + 32 + (h << 3));
        const float4 b1 = *reinterpret_cast<const float4*>(ABa + ig * 64 + 32 + (h << 3) + 4);
        aiB[0] = b0.x; aiB[1] = b0.y; aiB[2] = b0.z; aiB[3] = b0.w;
        aiB[4] = b1.x; aiB[5] = b1.y; aiB[6] = b1.z; aiB[7] = b1.w;
    }
    // W_bgc A-frags (row g = p), hi/lo split
    f16x8 wbh0, wbl0, wbh1, wbl1;
    #pragma unroll
    for (int e = 0; e < 8; ++e) {
        const float v0 = W_bgc[(p << 6) + (h << 3) + e];
        const f16 x0 = (f16)v0; wbh0[e] = x0; wbl0[e] = (f16)(v0 - (float)x0);
        const float v1 = W_bgc[(p << 6) + 32 + (h << 3) + e];
        const f16 x1 = (f16)v1; wbh1[e] = x1; wbl1[e] = (f16)(v1 - (float)x1);
    }
    float bb4[4];
    #pragma unroll
    for (int r = 0; r < 4; ++r) bb4[r] = b_bgc[(h << 2) + r];

    const float cxi = gcx[ig], cyi = gcy[ig];
    const float ti  = 1e-3f * gw[ig];

    for (int l = tid; l < 512; l += 256) {
        const int jg = (bb << 9) + l;
        sJ[l] = make_float2(gcx[jg], gcy[jg]);
    }
    __syncthreads();

    // lane base into tiled-transposed table: tile (bb*32+jc), row d=8h(+e), col p
    const float* bt = ABbT + ((size_t)(bb << 5) << 10) + ((h << 3) << 4) + p;
    float curA[8], curB[8], nxtA[8], nxtB[8];
    #pragma unroll
    for (int e = 0; e < 8; ++e) {
        curA[e] = bt[(e << 4)];
        curB[e] = bt[(e << 4) + 512];    // d += 32 -> +32*16 floats
    }

    f16* sp = S + (((size_t)((bb << 4) + (h << 2))) << 18) + ((size_t)irow << 9) + p;

    union F16x8u { f16x8 v; f16x2 h[4]; };

    for (int jc = 0; jc < 32; ++jc) {
        if (jc < 31) {
            const float* nx = bt + ((jc + 1) << 10);   // next 16-box tile
            #pragma unroll
            for (int e = 0; e < 8; ++e) {
                nxtA[e] = nx[(e << 4)];
                nxtB[e] = nx[(e << 4) + 512];
            }
        }
        const float2 je = sJ[(jc << 4) + p];
        const float e0 = hw_log2(fmaxf(fabsf(cxi - je.x), ti));
        const float e1 = hw_log2(fmaxf(fabsf(cyi - je.y), ti));

        F16x8u hhA, hlA, hhB, hlB;
        #pragma unroll
        for (int k = 0; k < 4; ++k) {
            float tv[2], uv[2];
            #pragma unroll
            for (int s = 0; s < 2; ++s) {
                const int e = (k << 1) + s;
                // arg already scaled by 2log2e: tanh(x) = 1 - 2/(exp2(arg)+1)
                float t = fmaf(e0, wA[e].x, fmaf(e1, wA[e].y, aiA[e] - curA[e]));
                tv[s] = fmaf(-2.0f, __builtin_amdgcn_rcpf(hw_exp2(t) + 1.0f), 1.0f);
                float u = fmaf(e0, wB[e].x, fmaf(e1, wB[e].y, aiB[e] - curB[e]));
                uv[s] = fmaf(-2.0f, __builtin_amdgcn_rcpf(hw_exp2(u) + 1.0f), 1.0f);
            }
            // mask-split: keep 10 mantissa bits -> exact under RTZ f16 convert
            const float th0 = __uint_as_float(__float_as_uint(tv[0]) & 0xFFFFE000u);
            const float th1 = __uint_as_float(__float_as_uint(tv[1]) & 0xFFFFE000u);
            hhA.h[k] = cvt_pk(th0, th1);
            hlA.h[k] = cvt_pk(tv[0] - th0, tv[1] - th1);
            const float uh0 = __uint_as_float(__float_as_uint(uv[0]) & 0xFFFFE000u);
            const float uh1 = __uint_as_float(__float_as_uint(uv[1]) & 0xFFFFE000u);
            hhB.h[k] = cvt_pk(uh0, uh1);
            hlB.h[k] = cvt_pk(uv[0] - uh0, uv[1] - uh1);
        }
        f32x4 acc = {0.f, 0.f, 0.f, 0.f};
        acc = __builtin_amdgcn_mfma_f32_16x16x32_f16(wbh0, hhA.v, acc, 0, 0, 0);
        acc = __builtin_amdgcn_mfma_f32_16x16x32_f16(wbh0, hlA.v, acc, 0, 0, 0);
        acc = __builtin_amdgcn_mfma_f32_16x16x32_f16(wbl0, hhA.v, acc, 0, 0, 0);
        acc = __builtin_amdgcn_mfma_f32_16x16x32_f16(wbh1, hhB.v, acc, 0, 0, 0);
        acc = __builtin_amdgcn_mfma_f32_16x16x32_f16(wbh1, hlB.v, acc, 0, 0, 0);
        acc = __builtin_amdgcn_mfma_f32_16x16x32_f16(wbl1, hhB.v, acc, 0, 0, 0);

        #pragma unroll
        for (int r = 0; r < 4; ++r)
            sp[((size_t)r << 18) + (jc << 4)] = (f16)fmaxf(acc[r] + bb4[r], 1e-6f);

        #pragma unroll
        for (int e = 0; e < 8; ++e) { curA[e] = nxtA[e]; curB[e] = nxtB[e]; }
    }
}

// ---------------- fused logits + softmax + PV. Per block: (z, 16 i-rows).
__global__ __launch_bounds__(256) void attn_fused(
    const f16* __restrict__ qp, const f16* __restrict__ kp,
    const f16* __restrict__ Sb, const f16* __restrict__ Yt,
    const float* __restrict__ b_gc, float* __restrict__ out)
{
    __shared__ float Ss[16][514];   // ~33 KB
    __shared__ f16   P[16 * 512];   // 16 KB

    const int tid  = threadIdx.x;
    const int lane = tid & 63;
    const int w    = tid >> 6;
    const int h    = lane >> 4;
    const int p_   = lane & 15;
    const int kgrp = h << 3;
    const int i0   = blockIdx.x << 4;
    const int z    = blockIdx.y;
    const int b    = z >> 4, g = z & 15;

    const char* qbytes = (const char*)qp + ((size_t)((b << 9) + i0)) * 2048 + (g << 7);
    const char* kbytes = (const char*)kp + ((size_t)(b << 9)) * 2048 + (g << 7);

    // q A-frags direct from global (A row = i = p_)
    f16x8 aq[2];
    {
        const char* qrow = qbytes + (size_t)p_ * 2048;
        #pragma unroll
        for (int s = 0; s < 2; ++s) {
            const int bo = ((s << 5) + kgrp) ^ ((p_ & 7) << 3);
            aq[s] = *reinterpret_cast<const f16x8*>(qrow + bo * 2);
        }
    }

    // ---- logits: each wave owns j in [w*128, w*128+128)
    #pragma unroll
    for (int f = 0; f < 8; ++f) {
        const int j = (w << 7) + (f << 4) + p_;
        const char* krow = kbytes + (size_t)j * 2048;
        f32x4 a = {0.f, 0.f, 0.f, 0.f};
        #pragma unroll
        for (int s = 0; s < 2; ++s) {
            const int bo = ((s << 5) + kgrp) ^ ((j & 7) << 3);
            const f16x8 bk = *reinterpret_cast<const f16x8*>(krow + bo * 2);
            a = __builtin_amdgcn_mfma_f32_16x16x32_f16(aq[s], bk, a, 0, 0, 0);
        }
        #pragma unroll
        for (int r = 0; r < 4; ++r)
            Ss[(h << 2) + r][(w << 7) + (f << 4) + p_] = 0.125f * a[r];
    }
    __syncthreads();

    // ---- softmax with geo-weight multiply (4 rows per wave)
    #pragma unroll
    for (int rr = 0; rr < 4; ++rr) {
        const int row = (w << 2) + rr;
        const f16* wbp = Sb + ((size_t)z << 18) + ((size_t)(i0 + row) << 9);
        float l[8];
        float m = -3.0e38f;
        #pragma unroll
        for (int t = 0; t < 8; ++t) { l[t] = Ss[row][(t << 6) + lane]; m = fmaxf(m, l[t]); }
        #pragma unroll
        for (int off = 32; off > 0; off >>= 1) m = fmaxf(m, __shfl_xor(m, off));
        float wb[8];
        #pragma unroll
        for (int t = 0; t < 8; ++t) wb[t] = (float)wbp[(t << 6) + lane];
        float ssum = 0.f;
        #pragma unroll
        for (int t = 0; t < 8; ++t) { l[t] = wb[t] * __expf(l[t] - m); ssum += l[t]; }
        #pragma unroll
        for (int off = 32; off > 0; off >>= 1) ssum += __shfl_xor(ssum, off);
        const float inv = 1.0f / ssum;
        const int sw = (row & 7) << 3;
        f16* prow = P + (row << 9);
        #pragma unroll
        for (int t = 0; t < 8; ++t)
            prow[(t << 6) + (lane ^ sw)] = (f16)(l[t] * inv);
    }
    __syncthreads();

    // ---- PV: out 16i x 64o; wave w owns o-frag [w*16, w*16+16)
    const int o = (w << 4) + p_;
    const f16* ytz = Yt + ((size_t)z << 15) + ((size_t)o << 9);
    const f16* pr  = P + (p_ << 9);
    f32x4 av = {0.f, 0.f, 0.f, 0.f};
    #pragma unroll
    for (int t = 0; t < 8; ++t) {
        #pragma unroll
        for (int s = 0; s < 2; ++s) {
            const int ko = (s << 5) + kgrp;
            const f16x8 bf = *reinterpret_cast<const f16x8*>(ytz + (t << 6) + (ko ^ ((o  & 7) << 3)));
            const f16x8 af = *reinterpret_cast<const f16x8*>(pr  + (t << 6) + (ko ^ ((p_ & 7) << 3)));
            av = __builtin_amdgcn_mfma_f32_16x16x32_f16(af, bf, av, 0, 0, 0);
        }
    }
    const float bg = b_gc[(g << 6) + o];
    float* orow = out + ((size_t)((b << 9) + i0)) * 1024 + (g << 6) + o;
    #pragma unroll
    for (int r = 0; r < 4; ++r)
        orow[(size_t)((h << 2) + r) * 1024] = fmaxf(av[r] + bg, 0.f);
}

// ---------------------------------------------------------------- launch
extern "C" void kernel_launch(void* const* d_in, const int* in_sizes, int n_in,
                              void* d_out, int out_size, void* d_ws, size_t ws_size,
                              hipStream_t stream)
{
    (void)in_sizes; (void)n_in; (void)out_size; (void)ws_size;
    const float* x     = (const float*)d_in[0];
    const float* boxes = (const float*)d_in[1];
    const float* W_geo = (const float*)d_in[2];
    const float* b_geo = (const float*)d_in[3];
    const float* W_bgc = (const float*)d_in[4];
    const float* b_bgc = (const float*)d_in[5];
    const float* W_q   = (const float*)d_in[6];
    const float* b_q   = (const float*)d_in[7];
    const float* W_k   = (const float*)d_in[8];
    const float* b_k   = (const float*)d_in[9];
    const float* W_gc  = (const float*)d_in[10];
    const float* b_gc  = (const float*)d_in[11];
    float* out = (float*)d_out;

    float* fws = (float*)d_ws;
    float* gcx = fws;
    float* gcy = gcx + 4096;
    float* gw  = gcy + 4096;
    float* ABa  = gw + 4096;                      // [4096][64] f32 = 1 MB
    float* ABbT = ABa + 4096 * 64;                // [256][64][16] f32 = 1 MB
    f16* qp  = (f16*)(ABbT + 4096 * 64);          // [4096][1024] f16  8.4 MB
    f16* kp  = qp + (size_t)4096 * 1024;          // [4096][1024] f16  8.4 MB
    f16* ytp = kp + (size_t)4096 * 1024;          // [128][64][512] f16 8.4 MB
    f16* Sws = ytp + (size_t)128 * 64 * 512;      // [128][512][512] f16 67.1 MB

    // pack scratch aliased into Sws head (consumed before geo_mfma writes Sws)
    f16* xs  = Sws;                               // [4096][1024] f16 8.4 MB
    f16* wqs = xs  + (size_t)4096 * 1024;
    f16* wks = wqs + (size_t)1024 * 1024;
    f16* wgs = wks + (size_t)1024 * 1024;

    geom_ab_kernel<<<1024, 256, 0, stream>>>(boxes, W_geo, b_geo, gcx, gcy, gw, ABa, ABbT);
    pack4_kernel<<<7168, 256, 0, stream>>>(x, W_q, W_k, W_gc, xs, wqs, wks, wgs);
    gemm_qk_f16<<<dim3(8, 32, 2), 512, 0, stream>>>(xs, wqs, wks, b_q, b_k, qp, kp);
    gemm_yt_f16<<<dim3(1, 4, 128), 256, 0, stream>>>(xs, wgs, ytp);
    geo_mfma<<<dim3(128, 8), 256, 0, stream>>>(gcx, gcy, gw, ABa, ABbT,
                                               W_geo, W_bgc, b_bgc, Sws);
    attn_fused<<<dim3(32, 128), 256, 0, stream>>>(qp, kp, Sws, ytp, b_gc, out);
}